// Round 8
// baseline (3881.810 us; speedup 1.0000x reference)
//
#include <hip/hip_runtime.h>

#define DEVI __device__ __forceinline__
typedef float f2 __attribute__((ext_vector_type(2)));
typedef unsigned u32x2 __attribute__((ext_vector_type(2)));

// ---------------- problem constants ----------------
constexpr int T_ = 4096, B_ = 128;
constexpr int CH = 8, NCH = T_ / CH;   // 512 chunks of 8 timesteps
constexpr int NSTEP2 = 528;            // mono kernel phases
constexpr int XROW = 68;               // x row padded 64->68 dwords

constexpr int Y1L = 2 * CH * 20;       // 320
constexpr int Y2L = 2 * CH * 12;       // 192

// split-kernel constants
constexpr int RQ = 16;                 // cross-WG ring depth (chunks)
constexpr int NSF = NCH + 8;           // 520 front phases
constexpr int NSB = NCH + 20;          // 532 back phases

struct P {
  const float* x;
  const float* w1; const float* b1;    // wih0 (20x64), bih0 (20)
  const float* wih[31]; const float* whh[31];
  const float* bih[31]; const float* bhh[31];
  float* out;
};

DEVI float ftanh(float x) {
  float e = __builtin_amdgcn_exp2f(x * 2.8853900817779268f);
  return 1.0f - 2.0f * __builtin_amdgcn_rcpf(e + 1.0f);
}

DEVI f2 pfma(f2 a, f2 b, f2 c) { return __builtin_elementwise_fma(a, b, c); }

// uniform half-dot over 10 floats of a 20-row: 2 ds_read_b128 + 1 ds_read_b64.
DEVI void acc20u(f2& a, const float* r128, const float* r64, const f2* w) {
  float4 v0 = ((const float4*)r128)[0];
  float4 v1 = ((const float4*)r128)[1];
  float2 v2 = *(const float2*)r64;
  union { float4 f; f2 h[2]; } u0, u1; u0.f = v0; u1.f = v1;
  f2 t; t.x = v2.x; t.y = v2.y;
  a = pfma(u0.h[0], w[0], a);
  a = pfma(u0.h[1], w[1], a);
  a = pfma(u1.h[0], w[2], a);
  a = pfma(u1.h[1], w[3], a);
  a = pfma(t, w[4], a);
}

// uniform half-dot over 6 slots of a 12-row: 1 b128 + 1 b64.
DEVI void acc12u(f2& a, const float* r128, const float* r64, const f2* w) {
  float4 v0 = *(const float4*)r128;
  float2 v2 = *(const float2*)r64;
  union { float4 f; f2 h[2]; } u; u.f = v0;
  f2 t; t.x = v2.x; t.y = v2.y;
  a = pfma(u.h[0], w[0], a);
  a = pfma(u.h[1], w[1], a);
  a = pfma(t, w[2], a);
}

// full dot over 10 floats of a 12-padded row (off-chain, uniform)
DEVI float dot10(const float* r, const f2* w) {
  float4 v0 = ((const float4*)r)[0];
  float4 v1 = ((const float4*)r)[1];
  float2 v2 = *(const float2*)(r + 8);
  union { float4 f; f2 h[2]; } u0, u1; u0.f = v0; u1.f = v1;
  f2 a0{0.f, 0.f}, a1{0.f, 0.f};
  a0 = pfma(u0.h[0], w[0], a0);
  a1 = pfma(u0.h[1], w[1], a1);
  a0 = pfma(u1.h[0], w[2], a0);
  a1 = pfma(u1.h[1], w[3], a1);
  f2 t; t.x = v2.x; t.y = v2.y;
  a0 = pfma(t, w[4], a0);
  f2 s = a0 + a1;
  return s.x + s.y;
}

// cross-half combine via v_permlane32_swap_b32 (VALU-class, off the LDS pipe)
DEVI float redsum(f2 a) {
  const float s = a.x + a.y;
  u32x2 r = __builtin_amdgcn_permlane32_swap(__float_as_uint(s),
                                             __float_as_uint(s), false, false);
  return __uint_as_float(r.x) + __uint_as_float(r.y);
}

// ================= proj / L30 chunk bodies =================
template <int SL>
DEVI void proj_chunk(const float* xbh, float* xww, const f2* wp, float bp,
                     bool hi) {
#pragma unroll
  for (int tt = 0; tt < CH; tt++) {
    const float* xr = xbh + SL * (CH * XROW) + tt * XROW;
    f2 a; a.x = bp; a.y = 0.f;
#pragma unroll
    for (int q = 0; q < 8; q++) {
      float4 v = ((const float4*)xr)[q];
      union { float4 f; f2 h[2]; } u; u.f = v;
      a = pfma(u.h[0], wp[2 * q], a);
      a = pfma(u.h[1], wp[2 * q + 1], a);
    }
    const float s = redsum(a);
    if (!hi) xww[SL * (CH * 20) + tt * 20] = s;
  }
}

template <int SL>
DEVI void l30_chunk(const float* y29, const f2* wi30, float b30, float wh30,
                    float& h30, float*& optr, bool st) {
#pragma unroll
  for (int tt = 0; tt < CH; tt++) {
    const float d = dot10(y29 + SL * (CH * 12) + tt * 12, wi30);
    h30 = ftanh(fmaf(h30, wh30, d + b30));
    if (st) optr[tt * B_] = h30;
  }
  optr += CH * B_;
}

// ================= mono wave 0 (fallback kernel) =================
DEVI void stage_proj(const P& p, int b, int lane, float* xb, float* xwf,
                     const float* y29) {
  const int jj = lane & 31;
  const bool act = jj < 20;
  const bool hi = lane >= 32;
  const int j = act ? jj : 19;
  const int ko = hi ? 32 : 0;
  f2 wp[16];
#pragma unroll
  for (int k = 0; k < 16; k++) {
    wp[k].x = p.w1[j * 64 + ko + 2 * k]; wp[k].y = p.w1[j * 64 + ko + 2 * k + 1];
  }
  const float bp = hi ? 0.f : p.b1[j];
  float* xww = xwf + j;
  const float* xbh = xb + ko;

  f2 wi30[5];
#pragma unroll
  for (int k = 0; k < 5; k++) {
    wi30[k].x = p.wih[30][2 * k];
    wi30[k].y = p.wih[30][2 * k + 1];
  }
  const float b30 = p.bih[30][0] + p.bhh[30][0];
  const float wh30 = p.whh[30][0];
  float h30 = 0.f;
  float* optr = p.out + b;
  const bool st = (lane == 0);

  const int tq = lane >> 4, qq = lane & 15;
  const float* src[2]; int dst[2];
#pragma unroll
  for (int r = 0; r < 2; r++) {
    const int row = r * 4 + tq;
    src[r] = p.x + (size_t)row * (B_ * 64) + (size_t)b * 64 + qq * 4;
    dst[r] = row * XROW + qq * 4;
  }
  float4 pf[2];
#pragma unroll
  for (int r = 0; r < 2; r++) pf[r] = *(const float4*)src[r];
#pragma unroll
  for (int r = 0; r < 2; r++) *(float4*)(xb + dst[r]) = pf[r];
#pragma unroll
  for (int r = 0; r < 2; r++) src[r] += CH * B_ * 64;

  for (int s = 0; s < NSTEP2; s += 2) {
    {
      const int c = s;
      if (c < NCH) {
        const bool more = (c + 1 < NCH);
        float4 nx[2];
        if (more) {
#pragma unroll
          for (int r = 0; r < 2; r++) { nx[r] = *(const float4*)src[r]; src[r] += CH * B_ * 64; }
        }
        if (act) proj_chunk<0>(xbh, xww, wp, bp, hi);
        if (more) {
#pragma unroll
          for (int r = 0; r < 2; r++) *(float4*)(xb + CH * XROW + dst[r]) = nx[r];
        }
      }
      if ((unsigned)(s - 16) < (unsigned)NCH)
        l30_chunk<0>(y29, wi30, b30, wh30, h30, optr, st);
      __syncthreads();
    }
    {
      const int c = s + 1;
      if (c < NCH) {
        const bool more = (c + 1 < NCH);
        float4 nx[2];
        if (more) {
#pragma unroll
          for (int r = 0; r < 2; r++) { nx[r] = *(const float4*)src[r]; src[r] += CH * B_ * 64; }
        }
        if (act) proj_chunk<1>(xbh, xww, wp, bp, hi);
        if (more) {
#pragma unroll
          for (int r = 0; r < 2; r++) *(float4*)(xb + dst[r]) = nx[r];
        }
      }
      if ((unsigned)(s + 1 - 16) < (unsigned)NCH)
        l30_chunk<1>(y29, wi30, b30, wh30, h30, optr, st);
      __syncthreads();
    }
  }
  if (st) p.out[T_ * B_ + b] = h30;
}

// ================= split-front wave 0: staging + proj only =================
DEVI void stage_proj_f(const P& p, int b, int lane, float* xb, float* xwf,
                       int nstep) {
  const int jj = lane & 31;
  const bool act = jj < 20;
  const bool hi = lane >= 32;
  const int j = act ? jj : 19;
  const int ko = hi ? 32 : 0;
  f2 wp[16];
#pragma unroll
  for (int k = 0; k < 16; k++) {
    wp[k].x = p.w1[j * 64 + ko + 2 * k]; wp[k].y = p.w1[j * 64 + ko + 2 * k + 1];
  }
  const float bp = hi ? 0.f : p.b1[j];
  float* xww = xwf + j;
  const float* xbh = xb + ko;

  const int tq = lane >> 4, qq = lane & 15;
  const float* src[2]; int dst[2];
#pragma unroll
  for (int r = 0; r < 2; r++) {
    const int row = r * 4 + tq;
    src[r] = p.x + (size_t)row * (B_ * 64) + (size_t)b * 64 + qq * 4;
    dst[r] = row * XROW + qq * 4;
  }
  float4 pf[2];
#pragma unroll
  for (int r = 0; r < 2; r++) pf[r] = *(const float4*)src[r];
#pragma unroll
  for (int r = 0; r < 2; r++) *(float4*)(xb + dst[r]) = pf[r];
#pragma unroll
  for (int r = 0; r < 2; r++) src[r] += CH * B_ * 64;

  for (int s = 0; s < nstep; s += 2) {
#pragma unroll
    for (int ph = 0; ph < 2; ph++) {
      const int c = s + ph;
      if (c < NCH) {
        const bool more = (c + 1 < NCH);
        float4 nx[2];
        if (more) {
#pragma unroll
          for (int r = 0; r < 2; r++) { nx[r] = *(const float4*)src[r]; src[r] += CH * B_ * 64; }
        }
        if (act) {
          if (c & 1) proj_chunk<1>(xbh, xww, wp, bp, hi);
          else       proj_chunk<0>(xbh, xww, wp, bp, hi);
        }
        if (more) {
          const int sl = ((c + 1) & 1) * (CH * XROW);
#pragma unroll
          for (int r = 0; r < 2; r++) *(float4*)(xb + sl + dst[r]) = nx[r];
        }
      }
      __syncthreads();
    }
  }
}

// ================= pair chunk (software-pipelined; optional ring export) ===
template <int SL, bool FIRST, bool PROD = false>
DEVI void pair_chunk(const float* yin, const float* yinB,
                     const float* yArA, const float* yArB, float* yAw,
                     const float* yBrA, const float* yBrB, float* yBw,
                     const f2* wiA, const f2* whA, const f2* wiB, const f2* whB,
                     float bA, float bB, bool hi, float* gw = nullptr) {
  constexpr int BASE = SL * (CH * 20);
  constexpr int PV0  = (1 - SL) * (CH * 20) + (CH - 1) * 20;
  {  // prologue: A(0)
    f2 a; a.x = bA; a.y = 0.f;
    if constexpr (FIRST) { const float pick = yin[BASE]; if (!hi) a.x += pick; }
    else acc20u(a, yin + BASE, yinB + BASE, wiA);
    acc20u(a, yArA + PV0, yArB + PV0, whA);
    yAw[BASE] = ftanh(redsum(a));
  }
#pragma unroll
  for (int tt = 1; tt < CH; tt++) {
    const int IN  = BASE + tt * 20;
    const int INp = IN - 20;
    const int PVB = (tt == 1) ? PV0 : (INp - 20);
    f2 bb; bb.x = bB; bb.y = 0.f;
    acc20u(bb, yArA + INp, yArB + INp, wiB);
    acc20u(bb, yBrA + PVB, yBrB + PVB, whB);
    f2 a; a.x = bA; a.y = 0.f;
    if constexpr (FIRST) { const float pick = yin[IN]; if (!hi) a.x += pick; }
    else acc20u(a, yin + IN, yinB + IN, wiA);
    acc20u(a, yArA + INp, yArB + INp, whA);
    const float hb = ftanh(redsum(bb));
    yBw[INp] = hb;
    if constexpr (PROD) { if (!hi) gw[(tt - 1) * 20] = hb; }
    yAw[IN] = ftanh(redsum(a));
  }
  {  // epilogue: B(CH-1)
    const int IN = BASE + (CH - 1) * 20;
    f2 bb; bb.x = bB; bb.y = 0.f;
    acc20u(bb, yArA + IN, yArB + IN, wiB);
    acc20u(bb, yBrA + IN - 20, yBrB + IN - 20, whB);
    const float hb = ftanh(redsum(bb));
    yBw[IN] = hb;
    if constexpr (PROD) { if (!hi) gw[(CH - 1) * 20] = hb; }
  }
}

// ================= mono stack1 pair driver =================
template <bool PH, bool FIRST>
DEVI void pair_s1(int la, int w, const P& p, int lane, float* y1f, float* xwf) {
  const int jj = lane & 31;
  const bool act = jj < 20;
  const bool hi = lane >= 32;
  const int j = act ? jj : 19;
  const int o128 = hi ? 12 : 0, o64 = hi ? 10 : 8;
  const int lb = la + 1;
  f2 whA[5], whB[5], wiB[5], wiA[FIRST ? 1 : 5];
#pragma unroll
  for (int q = 0; q < 5; q++) {
    const int tb = hi ? (q < 4 ? 12 + 2 * q : 10) : 2 * q;
    whA[q].x = p.whh[la][j * 20 + tb]; whA[q].y = p.whh[la][j * 20 + tb + 1];
    whB[q].x = p.whh[lb][j * 20 + tb]; whB[q].y = p.whh[lb][j * 20 + tb + 1];
    wiB[q].x = p.wih[lb][j * 20 + tb]; wiB[q].y = p.wih[lb][j * 20 + tb + 1];
    if constexpr (!FIRST) {
      wiA[q].x = p.wih[la][j * 20 + tb]; wiA[q].y = p.wih[la][j * 20 + tb + 1];
    }
  }
  float bA = p.bhh[la][j];
  if constexpr (!FIRST) bA += p.bih[la][j];
  float bB = p.bih[lb][j] + p.bhh[lb][j];
  if (hi) { bA = 0.f; bB = 0.f; }

  const float* yin  = FIRST ? (xwf + j) : (y1f + (la - 1) * Y1L + o128);
  const float* yinB = FIRST ? nullptr   : (y1f + (la - 1) * Y1L + o64);
  const float* yArA = y1f + la * Y1L + o128;
  const float* yArB = y1f + la * Y1L + o64;
  float*       yAw  = y1f + la * Y1L + j;
  const float* yBrA = y1f + lb * Y1L + o128;
  const float* yBrB = y1f + lb * Y1L + o64;
  float*       yBw  = y1f + lb * Y1L + j;
  if (act) { yAw[(2 * CH - 1) * 20] = 0.f; yBw[(2 * CH - 1) * 20] = 0.f; }

  for (int s = 0; s < NSTEP2; s += 2) {
    if ((unsigned)(s - w) < (unsigned)NCH && act)
      pair_chunk<PH ? 1 : 0, FIRST>(yin, yinB, yArA, yArB, yAw, yBrA, yBrB, yBw,
                                    wiA, whA, wiB, whB, bA, bB, hi);
    __syncthreads();
    if ((unsigned)(s + 1 - w) < (unsigned)NCH && act)
      pair_chunk<PH ? 0 : 1, FIRST>(yin, yinB, yArA, yArB, yAw, yBrA, yBrB, yBw,
                                    wiA, whA, wiB, whB, bA, bB, hi);
    __syncthreads();
  }
}

// ================= split pair driver (explicit rows; optional producer) ====
template <bool FIRST, bool PROD>
DEVI void pair_drv(int la, int w, int nstep, const P& p, int lane,
                   const float* xwf, const float* rIn, float* rA, float* rB,
                   float* gring, unsigned* prog, unsigned* cons) {
  const int jj = lane & 31;
  const bool act = jj < 20;
  const bool hi = lane >= 32;
  const int j = act ? jj : 19;
  const int o128 = hi ? 12 : 0, o64 = hi ? 10 : 8;
  const int lb = la + 1;
  f2 whA[5], whB[5], wiB[5], wiA[FIRST ? 1 : 5];
#pragma unroll
  for (int q = 0; q < 5; q++) {
    const int tb = hi ? (q < 4 ? 12 + 2 * q : 10) : 2 * q;
    whA[q].x = p.whh[la][j * 20 + tb]; whA[q].y = p.whh[la][j * 20 + tb + 1];
    whB[q].x = p.whh[lb][j * 20 + tb]; whB[q].y = p.whh[lb][j * 20 + tb + 1];
    wiB[q].x = p.wih[lb][j * 20 + tb]; wiB[q].y = p.wih[lb][j * 20 + tb + 1];
    if constexpr (!FIRST) {
      wiA[q].x = p.wih[la][j * 20 + tb]; wiA[q].y = p.wih[la][j * 20 + tb + 1];
    }
  }
  float bA = p.bhh[la][j];
  if constexpr (!FIRST) bA += p.bih[la][j];
  float bB = p.bih[lb][j] + p.bhh[lb][j];
  if (hi) { bA = 0.f; bB = 0.f; }

  const float* yin  = FIRST ? (xwf + j) : (rIn + o128);
  const float* yinB = FIRST ? nullptr   : (rIn + o64);
  const float* yArA = rA + o128; const float* yArB = rA + o64;
  float* yAw = rA + j;
  const float* yBrA = rB + o128; const float* yBrB = rB + o64;
  float* yBw = rB + j;
  if (act) { yAw[(2 * CH - 1) * 20] = 0.f; yBw[(2 * CH - 1) * 20] = 0.f; }

  for (int s = 0; s < nstep; s += 2) {
#pragma unroll
    for (int ph = 0; ph < 2; ph++) {
      const int c = s + ph - w;
      if ((unsigned)c < (unsigned)NCH && act) {
        float* gw = nullptr;
        if constexpr (PROD) {
          if (c >= RQ) {  // ring-full throttle (rarely taken)
            while ((int)c - (int)__hip_atomic_load(cons, __ATOMIC_RELAXED,
                     __HIP_MEMORY_SCOPE_AGENT) >= RQ)
              __builtin_amdgcn_s_sleep(8);
          }
          gw = gring + (c & (RQ - 1)) * (CH * 20) + j;
        }
        if (c & 1)
          pair_chunk<1, FIRST, PROD>(yin, yinB, yArA, yArB, yAw, yBrA, yBrB,
                                     yBw, wiA, whA, wiB, whB, bA, bB, hi, gw);
        else
          pair_chunk<0, FIRST, PROD>(yin, yinB, yArA, yArB, yAw, yBrA, yBrB,
                                     yBw, wiA, whA, wiB, whB, bA, bB, hi, gw);
        if constexpr (PROD) {
          if (lane == 0)
            __hip_atomic_store(prog, (unsigned)(c + 1), __ATOMIC_RELEASE,
                               __HIP_MEMORY_SCOPE_AGENT);
        }
      }
      __syncthreads();
    }
  }
}

// ================= stack2 pair chunk =================
template <int SL, bool WIDE>
DEVI void s2pair_chunk(const float* yi0A, const float* yi0B,
                       const float* rArA, const float* rArB, float* rAw,
                       const float* rBrA, const float* rBrB, float* rBw,
                       const f2* wiA, const f2* whA, const f2* wiB, const f2* whB,
                       float bA, float bB) {
  constexpr int B1  = SL * (CH * 20);
  constexpr int B2  = SL * (CH * 12);
  constexpr int PV0 = (1 - SL) * (CH * 12) + (CH - 1) * 12;
  {
    f2 a; a.x = bA; a.y = 0.f;
    if constexpr (WIDE) acc20u(a, yi0A + B1, yi0B + B1, wiA);
    else                acc12u(a, yi0A + B2, yi0B + B2, wiA);
    acc12u(a, rArA + PV0, rArB + PV0, whA);
    rAw[B2] = ftanh(redsum(a));
  }
#pragma unroll
  for (int tt = 1; tt < CH; tt++) {
    const int IN2 = B2 + tt * 12;
    const int INp = IN2 - 12;
    const int PVB = (tt == 1) ? PV0 : (INp - 12);
    f2 bb; bb.x = bB; bb.y = 0.f;
    acc12u(bb, rArA + INp, rArB + INp, wiB);
    acc12u(bb, rBrA + PVB, rBrB + PVB, whB);
    f2 a; a.x = bA; a.y = 0.f;
    if constexpr (WIDE) { const int IN1 = B1 + tt * 20; acc20u(a, yi0A + IN1, yi0B + IN1, wiA); }
    else                acc12u(a, yi0A + IN2, yi0B + IN2, wiA);
    acc12u(a, rArA + INp, rArB + INp, whA);
    rBw[INp] = ftanh(redsum(bb));
    rAw[IN2] = ftanh(redsum(a));
  }
  {
    const int IN2 = B2 + (CH - 1) * 12;
    f2 bb; bb.x = bB; bb.y = 0.f;
    acc12u(bb, rArA + IN2, rArB + IN2, wiB);
    acc12u(bb, rBrA + IN2 - 12, rBrB + IN2 - 12, whB);
    rBw[IN2] = ftanh(redsum(bb));
  }
}

// ================= mono stack2 driver =================
template <bool PH, bool WIDE>
DEVI void s2pair(int lA, int w, int rin, const P& p, int lane,
                 float* y1f, float* y2f) {
  const int jj = lane & 31;
  const bool act = jj < 10;
  const bool hi = lane >= 32;
  const int j = act ? jj : 9;
  const int o128w = hi ? 12 : 0, o64w = hi ? 10 : 8;
  const int o128s = hi ? 8 : 0,  o64s = hi ? 6 : 4;
  const int lB = lA + 1;
  f2 wiA[WIDE ? 5 : 3], whA[3], wiB[3], whB[3];
  if constexpr (WIDE) {
#pragma unroll
    for (int q = 0; q < 5; q++) {
      const int tb = hi ? (q < 4 ? 12 + 2 * q : 10) : 2 * q;
      wiA[q].x = p.wih[lA][j * 20 + tb];
      wiA[q].y = p.wih[lA][j * 20 + tb + 1];
    }
  } else {
#pragma unroll
    for (int q = 0; q < 3; q++) {
      const int tb = hi ? (q == 0 ? 8 : q == 1 ? 10 : 6) : 2 * q;
      wiA[q].x = tb     < 10 ? p.wih[lA][j * 10 + tb]     : 0.f;
      wiA[q].y = tb + 1 < 10 ? p.wih[lA][j * 10 + tb + 1] : 0.f;
    }
  }
#pragma unroll
  for (int q = 0; q < 3; q++) {
    const int tb = hi ? (q == 0 ? 8 : q == 1 ? 10 : 6) : 2 * q;
    whA[q].x = tb     < 10 ? p.whh[lA][j * 10 + tb]     : 0.f;
    whA[q].y = tb + 1 < 10 ? p.whh[lA][j * 10 + tb + 1] : 0.f;
    wiB[q].x = tb     < 10 ? p.wih[lB][j * 10 + tb]     : 0.f;
    wiB[q].y = tb + 1 < 10 ? p.wih[lB][j * 10 + tb + 1] : 0.f;
    whB[q].x = tb     < 10 ? p.whh[lB][j * 10 + tb]     : 0.f;
    whB[q].y = tb + 1 < 10 ? p.whh[lB][j * 10 + tb + 1] : 0.f;
  }
  const float bA = hi ? 0.f : (p.bih[lA][j] + p.bhh[lA][j]);
  const float bB = hi ? 0.f : (p.bih[lB][j] + p.bhh[lB][j]);

  const int rA = lA - 20;
  const float* yi0A = WIDE ? (y1f + 19 * Y1L + o128w) : (y2f + rin * Y2L + o128s);
  const float* yi0B = WIDE ? (y1f + 19 * Y1L + o64w)  : (y2f + rin * Y2L + o64s);
  const float* rArA = y2f + rA * Y2L + o128s;
  const float* rArB = y2f + rA * Y2L + o64s;
  float*       rAw  = y2f + rA * Y2L + j;
  const float* rBrA = y2f + (rA + 1) * Y2L + o128s;
  const float* rBrB = y2f + (rA + 1) * Y2L + o64s;
  float*       rBw  = y2f + (rA + 1) * Y2L + j;

  if constexpr (WIDE) {
    for (int q = lane; q < 10 * Y2L; q += 64) y2f[q] = 0.f;
  }

  for (int s = 0; s < NSTEP2; s += 2) {
    if ((unsigned)(s - w) < (unsigned)NCH && act)
      s2pair_chunk<PH ? 1 : 0, WIDE>(yi0A, yi0B, rArA, rArB, rAw, rBrA, rBrB, rBw,
                                     wiA, whA, wiB, whB, bA, bB);
    __syncthreads();
    if ((unsigned)(s + 1 - w) < (unsigned)NCH && act)
      s2pair_chunk<PH ? 0 : 1, WIDE>(yi0A, yi0B, rArA, rArB, rAw, rBrA, rBrB, rBw,
                                     wiA, whA, wiB, whB, bA, bB);
    __syncthreads();
  }
}

// ================= split stack2 driver (explicit rows) =================
template <bool WIDE>
DEVI void s2_drv(int lA, int w, int nstep, const P& p, int lane,
                 const float* wideRow, const float* rinRow, float* y2f) {
  const int jj = lane & 31;
  const bool act = jj < 10;
  const bool hi = lane >= 32;
  const int j = act ? jj : 9;
  const int o128w = hi ? 12 : 0, o64w = hi ? 10 : 8;
  const int o128s = hi ? 8 : 0,  o64s = hi ? 6 : 4;
  const int lB = lA + 1;
  f2 wiA[WIDE ? 5 : 3], whA[3], wiB[3], whB[3];
  if constexpr (WIDE) {
#pragma unroll
    for (int q = 0; q < 5; q++) {
      const int tb = hi ? (q < 4 ? 12 + 2 * q : 10) : 2 * q;
      wiA[q].x = p.wih[lA][j * 20 + tb];
      wiA[q].y = p.wih[lA][j * 20 + tb + 1];
    }
  } else {
#pragma unroll
    for (int q = 0; q < 3; q++) {
      const int tb = hi ? (q == 0 ? 8 : q == 1 ? 10 : 6) : 2 * q;
      wiA[q].x = tb     < 10 ? p.wih[lA][j * 10 + tb]     : 0.f;
      wiA[q].y = tb + 1 < 10 ? p.wih[lA][j * 10 + tb + 1] : 0.f;
    }
  }
#pragma unroll
  for (int q = 0; q < 3; q++) {
    const int tb = hi ? (q == 0 ? 8 : q == 1 ? 10 : 6) : 2 * q;
    whA[q].x = tb     < 10 ? p.whh[lA][j * 10 + tb]     : 0.f;
    whA[q].y = tb + 1 < 10 ? p.whh[lA][j * 10 + tb + 1] : 0.f;
    wiB[q].x = tb     < 10 ? p.wih[lB][j * 10 + tb]     : 0.f;
    wiB[q].y = tb + 1 < 10 ? p.wih[lB][j * 10 + tb + 1] : 0.f;
    whB[q].x = tb     < 10 ? p.whh[lB][j * 10 + tb]     : 0.f;
    whB[q].y = tb + 1 < 10 ? p.whh[lB][j * 10 + tb + 1] : 0.f;
  }
  const float bA = hi ? 0.f : (p.bih[lA][j] + p.bhh[lA][j]);
  const float bB = hi ? 0.f : (p.bih[lB][j] + p.bhh[lB][j]);

  const int rA = lA - 20;
  const float* yi0A = WIDE ? (wideRow + o128w) : (rinRow + o128s);
  const float* yi0B = WIDE ? (wideRow + o64w)  : (rinRow + o64s);
  const float* rArA = y2f + rA * Y2L + o128s;
  const float* rArB = y2f + rA * Y2L + o64s;
  float*       rAw  = y2f + rA * Y2L + j;
  const float* rBrA = y2f + (rA + 1) * Y2L + o128s;
  const float* rBrB = y2f + (rA + 1) * Y2L + o64s;
  float*       rBw  = y2f + (rA + 1) * Y2L + j;

  if constexpr (WIDE) {
    for (int q = lane; q < 10 * Y2L; q += 64) y2f[q] = 0.f;
  }

  for (int s = 0; s < nstep; s += 2) {
#pragma unroll
    for (int ph = 0; ph < 2; ph++) {
      const int c = s + ph - w;
      if ((unsigned)c < (unsigned)NCH && act) {
        if (c & 1)
          s2pair_chunk<1, WIDE>(yi0A, yi0B, rArA, rArB, rAw, rBrA, rBrB, rBw,
                                wiA, whA, wiB, whB, bA, bB);
        else
          s2pair_chunk<0, WIDE>(yi0A, yi0B, rArA, rArB, rAw, rBrA, rBrB, rBw,
                                wiA, whA, wiB, whB, bA, bB);
      }
      __syncthreads();
    }
  }
}

// ================= back wave 8: ring stager + L30 + stores =================
DEVI void stager_l30(const P& p, int b, int lane, float* row0, const float* y29,
                     const float* gring, unsigned* prog, unsigned* cons,
                     int nstep) {
  f2 wi30[5];
#pragma unroll
  for (int k = 0; k < 5; k++) {
    wi30[k].x = p.wih[30][2 * k];
    wi30[k].y = p.wih[30][2 * k + 1];
  }
  const float b30 = p.bih[30][0] + p.bhh[30][0];
  const float wh30 = p.whh[30][0];
  float h30 = 0.f;
  float* optr = p.out + b;
  const bool st = (lane == 0);

  for (int s = 0; s < nstep; s += 2) {
#pragma unroll
    for (int ph = 0; ph < 2; ph++) {
      const int sp = s + ph;
      const int cs = sp - 9;     // stage chunk cs -> consumed next phase (skew 10)
      if ((unsigned)cs < (unsigned)NCH) {
        while ((int)__hip_atomic_load(prog, __ATOMIC_ACQUIRE,
                 __HIP_MEMORY_SCOPE_AGENT) < cs + 1)
          __builtin_amdgcn_s_sleep(8);
        if (lane < 40) {
          const float4 v = *(const float4*)(gring + (cs & (RQ - 1)) * (CH * 20) + lane * 4);
          *(float4*)(row0 + (cs & 1) * (CH * 20) + lane * 4) = v;
        }
        if (lane == 0)
          __hip_atomic_store(cons, (unsigned)(cs + 1), __ATOMIC_RELAXED,
                             __HIP_MEMORY_SCOPE_AGENT);
      }
      const int cl = sp - 18;    // L30 chunk (L28,29 run at skew 17)
      if ((unsigned)cl < (unsigned)NCH) {
        if (cl & 1) l30_chunk<1>(y29, wi30, b30, wh30, h30, optr, st);
        else        l30_chunk<0>(y29, wi30, b30, wh30, h30, optr, st);
      }
      __syncthreads();
    }
  }
  if (st) p.out[T_ * B_ + b] = h30;  // hT
}

// ================= mono kernel (fallback, proven) =================
__global__ __launch_bounds__(1024, 1) void rnn_fused(P p) {
  __shared__ alignas(16) float xbuf[2 * CH * XROW];
  __shared__ alignas(16) float xw[2 * CH * 20];
  __shared__ alignas(16) float y1[20 * Y1L];
  __shared__ alignas(16) float y2[10 * Y2L];
  const int w = threadIdx.x >> 6, lane = threadIdx.x & 63, b = blockIdx.x;
  if (w == 0)       stage_proj(p, b, lane, xbuf, xw, y2 + 9 * Y2L);
  else if (w == 1)  pair_s1<true, true>(0, 1, p, lane, y1, xw);
  else if (w <= 10) {
    const int la = 2 * (w - 1);
    if (w & 1) pair_s1<true, false>(la, w, p, lane, y1, xw);
    else       pair_s1<false, false>(la, w, p, lane, y1, xw);
  }
  else if (w == 11) s2pair<true,  true >(20, 11, 0, p, lane, y1, y2);
  else if (w == 12) s2pair<false, false>(22, 12, 1, p, lane, y1, y2);
  else if (w == 13) s2pair<true,  false>(24, 13, 3, p, lane, y1, y2);
  else if (w == 14) s2pair<false, false>(26, 14, 5, p, lane, y1, y2);
  else              s2pair<true,  false>(28, 15, 7, p, lane, y1, y2);
}

// ================= split kernels =================
__global__ void rnn_init(unsigned* f) {
  if (threadIdx.x < 2 * B_) f[threadIdx.x] = 0;
}

// 2 WGs per batch: even blockIdx = front (proj + L0..L13), odd = back
// (L14..L29 + L30/stores + stager). Cross edge L13->L14 via global ring +
// agent-scope flags. 84KB LDS pad forces 1 WG/CU (256 WGs = 256 CUs).
__global__ __launch_bounds__(576) void rnn_split(P p, float* ring, unsigned* flags) {
  __shared__ alignas(16) float lds[21000];   // 84 KB: forces 1 WG/CU
  const int w = threadIdx.x >> 6, lane = threadIdx.x & 63;
  const int b = blockIdx.x >> 1, role = blockIdx.x & 1;
  float* gring = ring + (size_t)b * (RQ * CH * 20);
  unsigned* prog = flags + b;
  unsigned* cons = flags + B_ + b;

  if (role == 0) {  // front: proj + L0..L13 (8 waves + 1 idle)
    float* xbuf = lds;                 // 2*CH*XROW = 1088
    float* xw   = lds + 1088;          // 2*CH*20  = 320
    float* y1f  = lds + 1408;          // 14 rows x Y1L = 4480
    if (w == 0) {
      stage_proj_f(p, b, lane, xbuf, xw, NSF);
    } else if (w == 1) {
      pair_drv<true, false>(0, 1, NSF, p, lane, xw, nullptr,
                            y1f, y1f + Y1L, nullptr, nullptr, nullptr);
    } else if (w <= 6) {
      const int la = 2 * (w - 1);
      pair_drv<false, false>(la, w, NSF, p, lane, nullptr,
                             y1f + (la - 1) * Y1L, y1f + la * Y1L,
                             y1f + (la + 1) * Y1L, nullptr, nullptr, nullptr);
    } else if (w == 7) {  // producer: L12,13 -> global ring
      pair_drv<false, true>(12, 7, NSF, p, lane, nullptr,
                            y1f + 11 * Y1L, y1f + 12 * Y1L, y1f + 13 * Y1L,
                            gring, prog, cons);
    } else {  // idle wave: barrier participation only
      for (int s = 0; s < NSF; s += 2) { __syncthreads(); __syncthreads(); }
    }
  } else {          // back: L14..L30 (9 waves)
    float* y1b = lds;                  // 7 rows x Y1L = 2240 (row0 = staged L13)
    float* y2  = lds + 2240;           // 10 rows x Y2L = 1920
    if (w == 0) {
      pair_drv<false, false>(14, 10, NSB, p, lane, nullptr,
                             y1b, y1b + Y1L, y1b + 2 * Y1L, nullptr, nullptr, nullptr);
    } else if (w == 1) {
      pair_drv<false, false>(16, 11, NSB, p, lane, nullptr,
                             y1b + 2 * Y1L, y1b + 3 * Y1L, y1b + 4 * Y1L,
                             nullptr, nullptr, nullptr);
    } else if (w == 2) {
      pair_drv<false, false>(18, 12, NSB, p, lane, nullptr,
                             y1b + 4 * Y1L, y1b + 5 * Y1L, y1b + 6 * Y1L,
                             nullptr, nullptr, nullptr);
    }
    else if (w == 3) s2_drv<true >(20, 13, NSB, p, lane, y1b + 6 * Y1L, nullptr, y2);
    else if (w == 4) s2_drv<false>(22, 14, NSB, p, lane, nullptr, y2 + 1 * Y2L, y2);
    else if (w == 5) s2_drv<false>(24, 15, NSB, p, lane, nullptr, y2 + 3 * Y2L, y2);
    else if (w == 6) s2_drv<false>(26, 16, NSB, p, lane, nullptr, y2 + 5 * Y2L, y2);
    else if (w == 7) s2_drv<false>(28, 17, NSB, p, lane, nullptr, y2 + 7 * Y2L, y2);
    else stager_l30(p, b, lane, y1b, y2 + 9 * Y2L, gring, prog, cons, NSB);
  }
}

extern "C" void kernel_launch(void* const* d_in, const int* in_sizes, int n_in,
                              void* d_out, int out_size, void* d_ws, size_t ws_size,
                              hipStream_t stream) {
  (void)in_sizes; (void)out_size;
  if (n_in < 21) return;
  P p{};
  p.x  = (const float*)d_in[0];
  p.w1 = (const float*)d_in[1];
  p.b1 = (const float*)d_in[3];
  p.wih[0] = nullptr;              p.whh[0] = (const float*)d_in[2];
  p.bih[0] = nullptr;              p.bhh[0] = (const float*)d_in[4];
  for (int l = 1; l < 20; l++) {
    p.wih[l] = (const float*)d_in[5] + (l - 1) * 400;
    p.whh[l] = (const float*)d_in[6] + (l - 1) * 400;
    p.bih[l] = (const float*)d_in[7] + (l - 1) * 20;
    p.bhh[l] = (const float*)d_in[8] + (l - 1) * 20;
  }
  p.wih[20] = (const float*)d_in[9];   p.whh[20] = (const float*)d_in[10];
  p.bih[20] = (const float*)d_in[11];  p.bhh[20] = (const float*)d_in[12];
  for (int l = 21; l < 30; l++) {
    p.wih[l] = (const float*)d_in[13] + (l - 21) * 100;
    p.whh[l] = (const float*)d_in[14] + (l - 21) * 100;
    p.bih[l] = (const float*)d_in[15] + (l - 21) * 10;
    p.bhh[l] = (const float*)d_in[16] + (l - 21) * 10;
  }
  p.wih[30] = (const float*)d_in[17];  p.whh[30] = (const float*)d_in[18];
  p.bih[30] = (const float*)d_in[19];  p.bhh[30] = (const float*)d_in[20];
  p.out = (float*)d_out;

  const size_t ringBytes = (size_t)B_ * RQ * CH * 20 * sizeof(float);  // 1.31 MB
  const size_t need = ringBytes + 2 * B_ * sizeof(unsigned);
  if (d_ws != nullptr && ws_size >= need) {
    float* ring = (float*)d_ws;
    unsigned* flags = (unsigned*)((char*)d_ws + ringBytes);
    rnn_init<<<1, 256, 0, stream>>>(flags);
    rnn_split<<<2 * B_, 576, 0, stream>>>(p, ring, flags);
  } else {
    rnn_fused<<<B_, 1024, 0, stream>>>(p);
  }
}